// Round 1
// baseline (130.833 us; speedup 1.0000x reference)
//
#include <hip/hip_runtime.h>
#include <hip/hip_bf16.h>

#define BB 256
#define NLAT 128
#define HH 64
#define CC 64
#define GG 5000
#define BN_EPS 1e-5f

typedef __bf16 bf16x8 __attribute__((ext_vector_type(8)));
typedef float f32x4 __attribute__((ext_vector_type(4)));

// Kernel 1: h = BN(ReLU(latent @ W1 + b1)) -> bf16 [256][64]
__global__ void hprep_kernel(const float* __restrict__ latent,
                             const float* __restrict__ W1,
                             const float* __restrict__ b1,
                             const float* __restrict__ gamma,
                             const float* __restrict__ beta,
                             const float* __restrict__ mean,
                             const float* __restrict__ var,
                             unsigned short* __restrict__ hout) {
    const int b = blockIdx.x;   // 0..255
    const int c = threadIdx.x;  // 0..63
    float acc = b1[c];
    const float* lrow = latent + b * NLAT;
#pragma unroll 8
    for (int k = 0; k < NLAT; ++k)
        acc = fmaf(lrow[k], W1[k * HH + c], acc);
    acc = fmaxf(acc, 0.f);  // ReLU first
    float s = gamma[c] * rsqrtf(var[c] + BN_EPS);
    acc = (acc - mean[c]) * s + beta[c];
    __bf16 hv = (__bf16)acc;
    hout[b * HH + c] = *reinterpret_cast<unsigned short*>(&hv);
}

// Kernel 2: out[b,g,c] = sum_h h[b,h] * W[gene,h,c] + bias[gene,c]
// One block per gene; 4 waves; wave w owns rows [w*64, w*64+64).
__global__ __launch_bounds__(256) void decoder_kernel(
    const unsigned short* __restrict__ hbuf,  // bf16 [256][64]
    const int* __restrict__ genes,            // [5000]
    const float* __restrict__ wt,             // [30000][64][64]
    const float* __restrict__ bt,             // [30000][64]
    float* __restrict__ out)                  // [256][5000][64]
{
    // Wt (transposed W, bf16) with XOR swizzle: 64 c-rows x 128B = 8KB.
    __shared__ __align__(16) unsigned short lds[4096];

    const int tid = threadIdx.x;
    const int l   = tid & 63;
    const int w   = tid >> 6;   // wave id 0..3
    const int l16 = l & 15;
    const int lg  = l >> 4;     // 0..3
    const int g   = blockIdx.x;
    const int gene = genes[g];

    // --- A fragments (resident): h rows for this wave, k-contiguous 8 bf16
    bf16x8 afrag[4][2];
#pragma unroll
    for (int m = 0; m < 4; ++m) {
#pragma unroll
        for (int ks = 0; ks < 2; ++ks) {
            int row = w * 64 + m * 16 + l16;
            afrag[m][ks] = *reinterpret_cast<const bf16x8*>(
                hbuf + row * HH + ks * 32 + lg * 8);
        }
    }

    // --- stage W[gene] -> LDS bf16 transposed + swizzled
    // task (c, hb): read W[hb*8+j][c] j=0..7 (stride-256B, coalesced across c),
    // write 16B at byte offset c*128 + ((hb ^ (c&7)) * 16)
    const float* Wg = wt + (size_t)gene * (HH * CC);
#pragma unroll
    for (int it = 0; it < 2; ++it) {
        int task = it * 256 + tid;  // 0..511
        int c  = task & 63;
        int hb = task >> 6;         // 0..7
        bf16x8 pk;
#pragma unroll
        for (int j = 0; j < 8; ++j)
            pk[j] = (__bf16)Wg[(hb * 8 + j) * CC + c];
        int off16 = c * 8 + (hb ^ (c & 7));
        *reinterpret_cast<bf16x8*>(reinterpret_cast<char*>(lds) + off16 * 16) = pk;
    }

    // --- acc init from bias (overlaps staging latency)
    f32x4 acc[4][4];
#pragma unroll
    for (int n = 0; n < 4; ++n) {
        float bv = bt[(size_t)gene * CC + n * 16 + l16];
#pragma unroll
        for (int m = 0; m < 4; ++m) {
            acc[m][n][0] = bv; acc[m][n][1] = bv;
            acc[m][n][2] = bv; acc[m][n][3] = bv;
        }
    }

    __syncthreads();

    // --- B fragments: B[k][col], k-contiguous 8 per lane, col = n*16 + l16
    bf16x8 bfrag[4][2];
#pragma unroll
    for (int n = 0; n < 4; ++n) {
#pragma unroll
        for (int ks = 0; ks < 2; ++ks) {
            int c   = n * 16 + l16;
            int hbr = ks * 4 + lg;  // k-block 0..7
            int off16 = c * 8 + (hbr ^ (c & 7));
            bfrag[n][ks] = *reinterpret_cast<const bf16x8*>(
                reinterpret_cast<const char*>(lds) + off16 * 16);
        }
    }

    // --- MFMA: acc[m][n] += A[m,ks] * B[ks,n]
#pragma unroll
    for (int m = 0; m < 4; ++m)
#pragma unroll
        for (int n = 0; n < 4; ++n)
#pragma unroll
            for (int ks = 0; ks < 2; ++ks)
                acc[m][n] = __builtin_amdgcn_mfma_f32_16x16x32_bf16(
                    afrag[m][ks], bfrag[n][ks], acc[m][n], 0, 0, 0);

    // --- store: C/D layout col=l&15, row=(l>>4)*4+r
#pragma unroll
    for (int m = 0; m < 4; ++m) {
#pragma unroll
        for (int r = 0; r < 4; ++r) {
            int row = w * 64 + m * 16 + lg * 4 + r;
            float* orow = out + (size_t)row * (GG * CC) + (size_t)g * CC;
#pragma unroll
            for (int n = 0; n < 4; ++n)
                orow[n * 16 + l16] = acc[m][n][r];
        }
    }
}

extern "C" void kernel_launch(void* const* d_in, const int* in_sizes, int n_in,
                              void* d_out, int out_size, void* d_ws, size_t ws_size,
                              hipStream_t stream) {
    const float* latent = (const float*)d_in[0];
    const int*   genes  = (const int*)d_in[1];
    const float* W1     = (const float*)d_in[2];
    const float* b1     = (const float*)d_in[3];
    const float* gamma  = (const float*)d_in[4];
    const float* beta   = (const float*)d_in[5];
    const float* mean   = (const float*)d_in[6];
    const float* var    = (const float*)d_in[7];
    const float* wt     = (const float*)d_in[8];
    const float* bt     = (const float*)d_in[9];
    float* out = (float*)d_out;
    unsigned short* hbuf = (unsigned short*)d_ws;  // 32 KB bf16 h

    hprep_kernel<<<dim3(BB), dim3(HH), 0, stream>>>(latent, W1, b1, gamma, beta,
                                                    mean, var, hbuf);
    decoder_kernel<<<dim3(GG), dim3(256), 0, stream>>>(hbuf, genes, wt, bt, out);
}

// Round 2
// 121.870 us; speedup vs baseline: 1.0735x; 1.0735x over previous
//
#include <hip/hip_runtime.h>
#include <hip/hip_bf16.h>

#define BB 256
#define NLAT 128
#define HH 64
#define CC 64
#define GG 5000
#define NG 4
#define GSTRIDE (GG * CC)  // 320000 floats between batch rows
#define BN_EPS 1e-5f

typedef __bf16 bf16x8 __attribute__((ext_vector_type(8)));
typedef float f32x4 __attribute__((ext_vector_type(4)));

// Kernel 1: h = BN(ReLU(latent @ W1 + b1)) -> bf16 [256][64]
__global__ void hprep_kernel(const float* __restrict__ latent,
                             const float* __restrict__ W1,
                             const float* __restrict__ b1,
                             const float* __restrict__ gamma,
                             const float* __restrict__ beta,
                             const float* __restrict__ mean,
                             const float* __restrict__ var,
                             unsigned short* __restrict__ hout) {
    const int b = blockIdx.x;   // 0..255
    const int c = threadIdx.x;  // 0..63
    float acc = b1[c];
    const float* lrow = latent + b * NLAT;
#pragma unroll 8
    for (int k = 0; k < NLAT; ++k)
        acc = fmaf(lrow[k], W1[k * HH + c], acc);
    acc = fmaxf(acc, 0.f);  // ReLU first
    float s = gamma[c] * rsqrtf(var[c] + BN_EPS);
    acc = (acc - mean[c]) * s + beta[c];
    __bf16 hv = (__bf16)acc;
    hout[b * HH + c] = *reinterpret_cast<unsigned short*>(&hv);
}

// Barrier WITHOUT the __syncthreads memory fence: only drains LDS ops.
// Global stores stay in flight across gene iterations.
__device__ __forceinline__ void barrier_lds_only() {
    asm volatile("s_waitcnt lgkmcnt(0)" ::: "memory");
    __builtin_amdgcn_s_barrier();
    asm volatile("" ::: "memory");
}

// Kernel 2: out[b,g,c] = sum_h h[b,h] * W[gene,h,c] + bias[gene,c]
// 8 waves / 512 threads per block; wave w owns rows [w*32, w*32+32).
// Each block processes NG consecutive genes, double-buffered + pipelined:
//   iter i: [issue gene i+1 global loads] [ds_read+MFMA+store gene i]
//           [cvt + ds_write gene i+1] [lds-only barrier]
__global__ __launch_bounds__(512, 4) void decoder_kernel(
    const unsigned short* __restrict__ hbuf,  // bf16 [256][64]
    const int* __restrict__ genes,            // [5000]
    const float* __restrict__ wt,             // [30000][64][64] f32
    const float* __restrict__ bt,             // [30000][64] f32
    float* __restrict__ out)                  // [256][5000][64] f32
{
    __shared__ __align__(16) unsigned short lds[2][4096];  // 2 x 8 KB bf16 Wt

    const int tid = threadIdx.x;
    const int l   = tid & 63;
    const int w   = tid >> 6;   // wave 0..7
    const int l16 = l & 15;
    const int lg  = l >> 4;     // 0..3
    const int g0  = blockIdx.x * NG;

    // A fragments (persist across all NG genes): rows w*32 + m*16 + l16
    bf16x8 afrag[2][2];
#pragma unroll
    for (int m = 0; m < 2; ++m)
#pragma unroll
        for (int ks = 0; ks < 2; ++ks) {
            int row = w * 32 + m * 16 + l16;
            afrag[m][ks] = *reinterpret_cast<const bf16x8*>(
                hbuf + row * HH + ks * 32 + lg * 8);
        }

    // Staging geometry: this thread stages column sc of h-block shb.
    // Global read: Wg[(shb*8+j)*CC + sc], j=0..7 -> 256B coalesced per wave.
    // LDS write slot (16B units): transposed + XOR-swizzled.
    const int sc  = l;   // 0..63
    const int shb = w;   // 0..7
    const int swz16 = sc * 8 + (shb ^ (sc & 7));

    float pkv[8];

    // --- prologue: stage gene g0 into buf 0
    {
        const float* Wg = wt + (size_t)genes[g0] * (HH * CC);
#pragma unroll
        for (int j = 0; j < 8; ++j)
            pkv[j] = Wg[(shb * 8 + j) * CC + sc];
        bf16x8 pk;
#pragma unroll
        for (int j = 0; j < 8; ++j) pk[j] = (__bf16)pkv[j];
        *reinterpret_cast<bf16x8*>(
            reinterpret_cast<char*>(lds[0]) + swz16 * 16) = pk;
    }
    barrier_lds_only();

    int p = 0;
#pragma unroll
    for (int i = 0; i < NG; ++i) {
        const int g = g0 + i;

        // 1. issue next gene's global loads early (hide under MFMA+stores)
        if (i + 1 < NG) {
            const float* Wn = wt + (size_t)genes[g + 1] * (HH * CC);
#pragma unroll
            for (int j = 0; j < 8; ++j)
                pkv[j] = Wn[(shb * 8 + j) * CC + sc];
        }

        // 2. compute + store gene i (n-outer: live acc = 8 VGPRs)
        const float* bg = bt + (size_t)genes[g] * CC;
        const char* buf = reinterpret_cast<const char*>(lds[p]);
        float* og = out + (size_t)g * CC;
#pragma unroll
        for (int n = 0; n < 4; ++n) {
            const int c = n * 16 + l16;
            bf16x8 bfr0 = *reinterpret_cast<const bf16x8*>(
                buf + (c * 8 + ((0 + lg) ^ (c & 7))) * 16);
            bf16x8 bfr1 = *reinterpret_cast<const bf16x8*>(
                buf + (c * 8 + ((4 + lg) ^ (c & 7))) * 16);
            float bv = bg[c];
            f32x4 a0 = {bv, bv, bv, bv};
            f32x4 a1 = a0;
            a0 = __builtin_amdgcn_mfma_f32_16x16x32_bf16(afrag[0][0], bfr0, a0, 0, 0, 0);
            a0 = __builtin_amdgcn_mfma_f32_16x16x32_bf16(afrag[0][1], bfr1, a0, 0, 0, 0);
            a1 = __builtin_amdgcn_mfma_f32_16x16x32_bf16(afrag[1][0], bfr0, a1, 0, 0, 0);
            a1 = __builtin_amdgcn_mfma_f32_16x16x32_bf16(afrag[1][1], bfr1, a1, 0, 0, 0);
#pragma unroll
            for (int r = 0; r < 4; ++r) {
                int row0 = w * 32 + lg * 4 + r;  // m=0
                og[(size_t)row0 * GSTRIDE + c] = a0[r];
                og[(size_t)(row0 + 16) * GSTRIDE + c] = a1[r];
            }
        }

        // 3. cvt + ds_write next gene, lds-only barrier (stores keep flying)
        if (i + 1 < NG) {
            bf16x8 pk;
#pragma unroll
            for (int j = 0; j < 8; ++j) pk[j] = (__bf16)pkv[j];
            *reinterpret_cast<bf16x8*>(
                reinterpret_cast<char*>(lds[p ^ 1]) + swz16 * 16) = pk;
            barrier_lds_only();
            p ^= 1;
        }
    }
}

extern "C" void kernel_launch(void* const* d_in, const int* in_sizes, int n_in,
                              void* d_out, int out_size, void* d_ws, size_t ws_size,
                              hipStream_t stream) {
    const float* latent = (const float*)d_in[0];
    const int*   genes  = (const int*)d_in[1];
    const float* W1     = (const float*)d_in[2];
    const float* b1     = (const float*)d_in[3];
    const float* gamma  = (const float*)d_in[4];
    const float* beta   = (const float*)d_in[5];
    const float* mean   = (const float*)d_in[6];
    const float* var    = (const float*)d_in[7];
    const float* wt     = (const float*)d_in[8];
    const float* bt     = (const float*)d_in[9];
    float* out = (float*)d_out;
    unsigned short* hbuf = (unsigned short*)d_ws;  // 32 KB bf16 h

    hprep_kernel<<<dim3(BB), dim3(HH), 0, stream>>>(latent, W1, b1, gamma, beta,
                                                    mean, var, hbuf);
    decoder_kernel<<<dim3(GG / NG), dim3(512), 0, stream>>>(hbuf, genes, wt, bt, out);
}

// Round 3
// 101.072 us; speedup vs baseline: 1.2945x; 1.2058x over previous
//
#include <hip/hip_runtime.h>
#include <hip/hip_bf16.h>

#define BB 256
#define NLAT 128
#define HH 64
#define CC 64
#define GG 5000
#define NG 4
#define GSTRIDE (GG * CC)  // 320000 floats between batch rows
#define BN_EPS 1e-5f

typedef __bf16 bf16x8 __attribute__((ext_vector_type(8)));
typedef float f32x4 __attribute__((ext_vector_type(4)));

// Kernel 1: h = BN(ReLU(latent @ W1 + b1)) -> bf16 [256][64]
__global__ void hprep_kernel(const float* __restrict__ latent,
                             const float* __restrict__ W1,
                             const float* __restrict__ b1,
                             const float* __restrict__ gamma,
                             const float* __restrict__ beta,
                             const float* __restrict__ mean,
                             const float* __restrict__ var,
                             unsigned short* __restrict__ hout) {
    const int b = blockIdx.x;   // 0..255
    const int c = threadIdx.x;  // 0..63
    float acc = b1[c];
    const float* lrow = latent + b * NLAT;
#pragma unroll 8
    for (int k = 0; k < NLAT; ++k)
        acc = fmaf(lrow[k], W1[k * HH + c], acc);
    acc = fmaxf(acc, 0.f);  // ReLU first
    float s = gamma[c] * rsqrtf(var[c] + BN_EPS);
    acc = (acc - mean[c]) * s + beta[c];
    __bf16 hv = (__bf16)acc;
    hout[b * HH + c] = *reinterpret_cast<unsigned short*>(&hv);
}

// Barrier that only drains LDS ops; global loads/stores stay in flight.
__device__ __forceinline__ void barrier_lds_only() {
    asm volatile("s_waitcnt lgkmcnt(0)" ::: "memory");
    __builtin_amdgcn_s_barrier();
    asm volatile("" ::: "memory");
}

// Kernel 2: out[b,g,c] = sum_h h[b,h] * W[gene,h,c] + bias[gene,c]
// 8 waves / 512 threads; wave w owns rows [w*32, w*32+32).
// Operand-swapped MFMA: E = mfma(Bt_frag, A_frag) gives lane = (c 4-contig, b).
// Output staged per gene in 64 KB LDS, flushed as full 256B rows
// (16 lanes x dwordx4 = one contiguous (b,g) row -> full 128B lines only).
__global__ __launch_bounds__(512, 4) void decoder_kernel(
    const unsigned short* __restrict__ hbuf,  // bf16 [256][64]
    const int* __restrict__ genes,            // [5000]
    const float* __restrict__ wt,             // [30000][64][64] f32
    const float* __restrict__ bt,             // [30000][64] f32
    float* __restrict__ out)                  // [256][5000][64] f32
{
    __shared__ __align__(16) unsigned short ldsW[2][4096];  // 2 x 8 KB bf16 Wt
    __shared__ __align__(16) float ldsO[BB * CC];           // 64 KB out tile

    const int tid = threadIdx.x;
    const int l   = tid & 63;
    const int w   = tid >> 6;   // wave 0..7
    const int l16 = l & 15;
    const int lg  = l >> 4;     // 0..3
    const int g0  = blockIdx.x * NG;

    // A fragments (persist): rows w*32 + m*16 + l16, k-contiguous 8 bf16
    bf16x8 afrag[2][2];
#pragma unroll
    for (int m = 0; m < 2; ++m)
#pragma unroll
        for (int ks = 0; ks < 2; ++ks) {
            int row = w * 32 + m * 16 + l16;
            afrag[m][ks] = *reinterpret_cast<const bf16x8*>(
                hbuf + row * HH + ks * 32 + lg * 8);
        }

    // W staging geometry: thread stages column sc of h-block shb.
    const int sc  = l;   // 0..63
    const int shb = w;   // 0..7
    const int swz16 = sc * 8 + (shb ^ (sc & 7));

    float pkv[8];

    // --- prologue: stage gene g0 into ldsW[0]
    {
        const float* Wg = wt + (size_t)genes[g0] * (HH * CC);
#pragma unroll
        for (int j = 0; j < 8; ++j)
            pkv[j] = Wg[(shb * 8 + j) * CC + sc];
        bf16x8 pk;
#pragma unroll
        for (int j = 0; j < 8; ++j) pk[j] = (__bf16)pkv[j];
        *reinterpret_cast<bf16x8*>(
            reinterpret_cast<char*>(ldsW[0]) + swz16 * 16) = pk;
    }
    barrier_lds_only();

    int p = 0;
#pragma unroll
    for (int i = 0; i < NG; ++i) {
        const int g = g0 + i;

        // 1. issue next gene's gather loads early (hide under MFMA + flush)
        if (i + 1 < NG) {
            const float* Wn = wt + (size_t)genes[g + 1] * (HH * CC);
#pragma unroll
            for (int j = 0; j < 8; ++j)
                pkv[j] = Wn[(shb * 8 + j) * CC + sc];
        }

        // 2. MFMA (operand-swapped): E[n][m] lane = (c = n*16+lg*4+r, b = l16)
        const float* bg = bt + (size_t)genes[g] * CC;
        const char* buf = reinterpret_cast<const char*>(ldsW[p]);
        f32x4 E[4][2];
#pragma unroll
        for (int n = 0; n < 4; ++n) {
            const int c = n * 16 + l16;
            bf16x8 bfr0 = *reinterpret_cast<const bf16x8*>(
                buf + (c * 8 + ((0 + lg) ^ (c & 7))) * 16);
            bf16x8 bfr1 = *reinterpret_cast<const bf16x8*>(
                buf + (c * 8 + ((4 + lg) ^ (c & 7))) * 16);
            f32x4 binit = *reinterpret_cast<const f32x4*>(bg + n * 16 + lg * 4);
#pragma unroll
            for (int m = 0; m < 2; ++m) {
                f32x4 e = binit;
                e = __builtin_amdgcn_mfma_f32_16x16x32_bf16(bfr0, afrag[m][0], e, 0, 0, 0);
                e = __builtin_amdgcn_mfma_f32_16x16x32_bf16(bfr1, afrag[m][1], e, 0, 0, 0);
                E[n][m] = e;
            }
        }

        // 3. acc -> ldsO, chunk-XOR swizzled (2-way max = free)
#pragma unroll
        for (int n = 0; n < 4; ++n)
#pragma unroll
            for (int m = 0; m < 2; ++m) {
                int b = w * 32 + m * 16 + l16;
                int qp = (n * 4 + lg) ^ l16;
                *reinterpret_cast<f32x4*>(ldsO + b * CC + qp * 4) = E[n][m];
            }
        barrier_lds_only();

        // 4. flush: 16 lanes cover one full 256B (b,g) row; 4 rows/instr
        {
            float* og = out + (size_t)g * CC;
#pragma unroll
            for (int it = 0; it < 8; ++it) {
                int b  = it * 32 + w * 4 + lg;
                int qp = l16 ^ (b & 15);
                f32x4 v = *reinterpret_cast<const f32x4*>(ldsO + b * CC + qp * 4);
                *reinterpret_cast<f32x4*>(og + (size_t)b * GSTRIDE + l16 * 4) = v;
            }
        }

        // 5. cvt + ds_write next gene's Wt (stores keep flying)
        if (i + 1 < NG) {
            bf16x8 pk;
#pragma unroll
            for (int j = 0; j < 8; ++j) pk[j] = (__bf16)pkv[j];
            *reinterpret_cast<bf16x8*>(
                reinterpret_cast<char*>(ldsW[p ^ 1]) + swz16 * 16) = pk;
            p ^= 1;
        }
        barrier_lds_only();  // protects ldsO reuse + Wt buffer handoff
    }
}

extern "C" void kernel_launch(void* const* d_in, const int* in_sizes, int n_in,
                              void* d_out, int out_size, void* d_ws, size_t ws_size,
                              hipStream_t stream) {
    const float* latent = (const float*)d_in[0];
    const int*   genes  = (const int*)d_in[1];
    const float* W1     = (const float*)d_in[2];
    const float* b1     = (const float*)d_in[3];
    const float* gamma  = (const float*)d_in[4];
    const float* beta   = (const float*)d_in[5];
    const float* mean   = (const float*)d_in[6];
    const float* var    = (const float*)d_in[7];
    const float* wt     = (const float*)d_in[8];
    const float* bt     = (const float*)d_in[9];
    float* out = (float*)d_out;
    unsigned short* hbuf = (unsigned short*)d_ws;  // 32 KB bf16 h

    hprep_kernel<<<dim3(BB), dim3(HH), 0, stream>>>(latent, W1, b1, gamma, beta,
                                                    mean, var, hbuf);
    decoder_kernel<<<dim3(GG / NG), dim3(512), 0, stream>>>(hbuf, genes, wt, bt, out);
}